// Round 1
// baseline (228.375 us; speedup 1.0000x reference)
//
#include <hip/hip_runtime.h>
#include <math.h>

namespace {

constexpr int L = 1024;
constexpr int H = 8;
constexpr int E = 64;
// B = 2, BH = 16

__device__ __forceinline__ float rcp_fast(float x) { return __builtin_amdgcn_rcpf(x); }
__device__ __forceinline__ float tanh_fast(float x) {
  // tanh(x) = 1 - 2/(exp(2x)+1); saturates correctly at +-1 for large |x|
  return 1.0f - 2.0f * rcp_fast(__expf(2.0f * x) + 1.0f);
}
__device__ __forceinline__ float sigm_fast(float x) {
  return rcp_fast(1.0f + __expf(-x));
}

// -------------------------------------------------------------------------
// K1: scores[bh][l][s] = (1/8) * sum_e q[b,l,h,e] * k[b,s,h,e]
// grid (L/64, L/64, BH), block 256. 64x64 C-tile, 4x4 per thread, BK = E = 64.
// -------------------------------------------------------------------------
__global__ __launch_bounds__(256) void k_scores(
    const float* __restrict__ q, const float* __restrict__ k,
    float* __restrict__ sc)
{
  const int lt = blockIdx.x, st = blockIdx.y, bh = blockIdx.z;
  const int b = bh >> 3, h = bh & 7;
  __shared__ float As[64][68];  // As[e][l]   (transposed, pad for b128 reads)
  __shared__ float Bs[64][68];  // Bs[e][s]
  const int tid = threadIdx.x;
  const int r = tid >> 4, c4 = tid & 15;
  const float* qb = q + (((size_t)b * L + (size_t)lt * 64) * H + h) * E;
  const float* kb = k + (((size_t)b * L + (size_t)st * 64) * H + h) * E;
#pragma unroll
  for (int i = 0; i < 4; ++i) {
    int row = r + i * 16;
    float4 qa = *(const float4*)(qb + (size_t)row * (H * E) + c4 * 4);
    float4 ka = *(const float4*)(kb + (size_t)row * (H * E) + c4 * 4);
    As[c4 * 4 + 0][row] = qa.x; As[c4 * 4 + 1][row] = qa.y;
    As[c4 * 4 + 2][row] = qa.z; As[c4 * 4 + 3][row] = qa.w;
    Bs[c4 * 4 + 0][row] = ka.x; Bs[c4 * 4 + 1][row] = ka.y;
    Bs[c4 * 4 + 2][row] = ka.z; Bs[c4 * 4 + 3][row] = ka.w;
  }
  __syncthreads();
  const int tx = tid & 15, ty = tid >> 4;
  float acc[4][4] = {};
  for (int e = 0; e < 64; ++e) {
    float4 a = *(const float4*)&As[e][ty * 4];
    float4 bb = *(const float4*)&Bs[e][tx * 4];
    float av[4] = {a.x, a.y, a.z, a.w};
    float bv[4] = {bb.x, bb.y, bb.z, bb.w};
#pragma unroll
    for (int i = 0; i < 4; ++i)
#pragma unroll
      for (int j = 0; j < 4; ++j) acc[i][j] += av[i] * bv[j];
  }
  float* cb = sc + (((size_t)bh * L + (size_t)lt * 64) * L + (size_t)st * 64);
#pragma unroll
  for (int i = 0; i < 4; ++i) {
    float4 o = make_float4(acc[i][0] * 0.125f, acc[i][1] * 0.125f,
                           acc[i][2] * 0.125f, acc[i][3] * 0.125f);
    *(float4*)(cb + (size_t)(ty * 4 + i) * L + tx * 4) = o;
  }
}

// -------------------------------------------------------------------------
// K2: in-place transform scores -> att.
// att(l,s) = F(sc[l][s], sc[s][l]).  Each block owns tile pair (lt,st),(st,lt)
// with st >= lt; loads both coalesced, transposes through LDS, writes both.
// Diagonal: A_anti=0 -> tanh(0)=0 -> relu->0 -> att=0 automatically.
// grid (16,16,BH), block 256; blocks with st<lt exit.
// -------------------------------------------------------------------------
__global__ __launch_bounds__(256) void k_transform(
    float* __restrict__ att,
    const float* __restrict__ p_lgg, const float* __restrict__ p_ltg,
    const float* __restrict__ p_lgd, const float* __restrict__ p_ltd)
{
  const int st = blockIdx.x, lt = blockIdx.y, bh = blockIdx.z;
  if (st < lt) return;

  const float gg = fminf(fmaxf(__expf(p_lgg[0]), 1e-3f), 20.0f);
  const float tg = fminf(fmaxf(__expf(p_ltg[0]), 1e-3f), 10.0f);
  const float gd = fminf(fmaxf(__expf(p_lgd[0]), 1e-3f), 20.0f);
  const float td = fminf(fmaxf(__expf(p_ltd[0]), 1e-3f), 10.0f);
  const float inv_tg = 1.0f / tg;
  const float inv_td = 1.0f / td;
  const float gd_inv_td = gd * inv_td;

  __shared__ float T1t[64][65];  // T1t[j][i] = T1[i][j]
  __shared__ float T2t[64][65];
  const int tid = threadIdx.x;
  const int rl = tid >> 4, c4 = tid & 15;
  float* T1 = att + (((size_t)bh * L + (size_t)lt * 64) * L + (size_t)st * 64);
  float* T2 = att + (((size_t)bh * L + (size_t)st * 64) * L + (size_t)lt * 64);

  float4 t1r[4], t2r[4];
#pragma unroll
  for (int kk = 0; kk < 4; ++kk) {
    int row = rl * 4 + kk;
    t1r[kk] = *(const float4*)(T1 + (size_t)row * L + c4 * 4);
    t2r[kk] = *(const float4*)(T2 + (size_t)row * L + c4 * 4);
    T1t[c4 * 4 + 0][row] = t1r[kk].x; T1t[c4 * 4 + 1][row] = t1r[kk].y;
    T1t[c4 * 4 + 2][row] = t1r[kk].z; T1t[c4 * 4 + 3][row] = t1r[kk].w;
    T2t[c4 * 4 + 0][row] = t2r[kk].x; T2t[c4 * 4 + 1][row] = t2r[kk].y;
    T2t[c4 * 4 + 2][row] = t2r[kk].z; T2t[c4 * 4 + 3][row] = t2r[kk].w;
  }
  __syncthreads();

  auto F = [&](float x, float y) -> float {
    float Ss = 0.5f * (x + y);
    float Aa = 0.5f * (x - y);
    float gp = sigm_fast(gg * tanh_fast(Ss * inv_tg));
    float dp = sigm_fast(gd * tanh_fast(Aa * inv_td));
    float t = tanh_fast(Aa * gd_inv_td);
    return fmaxf(t, 0.0f) * gp * dp;
  };

#pragma unroll
  for (int kk = 0; kk < 4; ++kk) {
    int row = rl * 4 + kk;
    float y0 = T2t[row][c4 * 4 + 0], y1 = T2t[row][c4 * 4 + 1];
    float y2 = T2t[row][c4 * 4 + 2], y3 = T2t[row][c4 * 4 + 3];
    float z0 = T1t[row][c4 * 4 + 0], z1 = T1t[row][c4 * 4 + 1];
    float z2 = T1t[row][c4 * 4 + 2], z3 = T1t[row][c4 * 4 + 3];
    float4 o1 = make_float4(F(t1r[kk].x, y0), F(t1r[kk].y, y1),
                            F(t1r[kk].z, y2), F(t1r[kk].w, y3));
    float4 o2 = make_float4(F(t2r[kk].x, z0), F(t2r[kk].y, z1),
                            F(t2r[kk].z, z2), F(t2r[kk].w, z3));
    *(float4*)(T1 + (size_t)row * L + c4 * 4) = o1;
    *(float4*)(T2 + (size_t)row * L + c4 * 4) = o2;
  }
}

// -------------------------------------------------------------------------
// K3: V[b,l,h,e] = sum_s att[bh][l][s] * value[b,s,h,e]; entropy fused into
// the att-tile load (each loading thread owns one att row -> shuffle reduce).
// grid (L/32, BH), block 256. 32x64 out tile, 2x4 per thread, BK=32.
// -------------------------------------------------------------------------
__global__ __launch_bounds__(256) void k_pv(
    const float* __restrict__ att, const float* __restrict__ v,
    float* __restrict__ out, float* __restrict__ entr)
{
  const int mt = blockIdx.x;
  const int bh = blockIdx.y;
  const int b = bh >> 3, h = bh & 7;
  const int tid = threadIdx.x;
  __shared__ float At[32][36];  // At[k][m] (transposed att tile)
  __shared__ float Bs[32][68];  // Bs[k][e]
  const int l0 = mt * 32;
  const float* abase = att + ((size_t)bh * L + l0) * L;
  const float* vbase = v + ((size_t)b * L * H + h) * E;
  const int ar = tid >> 3, ac4 = tid & 7;
  const int br = tid >> 4, bc4 = tid & 15;
  const int tx = tid & 15, ty = tid >> 4;

  float acc0[4] = {0, 0, 0, 0}, acc1[4] = {0, 0, 0, 0};
  float ent = 0.0f;

  for (int k0 = 0; k0 < L; k0 += 32) {
    float4 av = *(const float4*)(abase + (size_t)ar * L + k0 + ac4 * 4);
    ent -= av.x * __logf(fmaxf(av.x, 1e-8f));
    ent -= av.y * __logf(fmaxf(av.y, 1e-8f));
    ent -= av.z * __logf(fmaxf(av.z, 1e-8f));
    ent -= av.w * __logf(fmaxf(av.w, 1e-8f));
    At[ac4 * 4 + 0][ar] = av.x; At[ac4 * 4 + 1][ar] = av.y;
    At[ac4 * 4 + 2][ar] = av.z; At[ac4 * 4 + 3][ar] = av.w;
    float4 b0 = *(const float4*)(vbase + (size_t)(k0 + br) * (H * E) + bc4 * 4);
    float4 b1 = *(const float4*)(vbase + (size_t)(k0 + br + 16) * (H * E) + bc4 * 4);
    *(float4*)&Bs[br][bc4 * 4] = b0;
    *(float4*)&Bs[br + 16][bc4 * 4] = b1;
    __syncthreads();
#pragma unroll
    for (int kk = 0; kk < 32; ++kk) {
      float a0 = At[kk][ty * 2 + 0];
      float a1 = At[kk][ty * 2 + 1];
      float4 bb = *(const float4*)&Bs[kk][tx * 4];
      acc0[0] += a0 * bb.x; acc0[1] += a0 * bb.y;
      acc0[2] += a0 * bb.z; acc0[3] += a0 * bb.w;
      acc1[0] += a1 * bb.x; acc1[1] += a1 * bb.y;
      acc1[2] += a1 * bb.z; acc1[3] += a1 * bb.w;
    }
    __syncthreads();
  }

  float* ob = out + (((size_t)b * L + l0 + ty * 2) * H + h) * E + tx * 4;
  *(float4*)(ob) = make_float4(acc0[0], acc0[1], acc0[2], acc0[3]);
  *(float4*)(ob + (size_t)H * E) = make_float4(acc1[0], acc1[1], acc1[2], acc1[3]);

  ent += __shfl_xor(ent, 1);
  ent += __shfl_xor(ent, 2);
  ent += __shfl_xor(ent, 4);
  if ((tid & 7) == 0) entr[(size_t)bh * L + l0 + ar] = ent;
}

}  // namespace

extern "C" void kernel_launch(void* const* d_in, const int* in_sizes, int n_in,
                              void* d_out, int out_size, void* d_ws, size_t ws_size,
                              hipStream_t stream) {
  const float* q = (const float*)d_in[0];
  const float* k = (const float*)d_in[1];
  const float* v = (const float*)d_in[2];
  // d_in[3..6]: mask_miss_k, mask_miss_q, pos, causal_mask — unused by reference
  const float* p_lgg = (const float*)d_in[7];
  const float* p_ltg = (const float*)d_in[8];
  const float* p_lgd = (const float*)d_in[9];
  const float* p_ltd = (const float*)d_in[10];

  float* Vout = (float*)d_out;                  // (B,L,H,E)   1,048,576
  float* att = Vout + 1048576;                  // (B,H,L,S)  16,777,216
  float* entr = att + 16777216;                 // (B,H,L)        16,384

  k_scores<<<dim3(16, 16, 16), 256, 0, stream>>>(q, k, att);
  k_transform<<<dim3(16, 16, 16), 256, 0, stream>>>(att, p_lgg, p_ltg, p_lgd, p_ltd);
  k_pv<<<dim3(32, 16), 256, 0, stream>>>(att, v, Vout, entr);
}

// Round 2
// 173.191 us; speedup vs baseline: 1.3186x; 1.3186x over previous
//
#include <hip/hip_runtime.h>
#include <math.h>

namespace {

typedef __bf16 bf16_t;
typedef bf16_t bf16x8 __attribute__((ext_vector_type(8)));
typedef bf16_t bf16x4 __attribute__((ext_vector_type(4)));
typedef bf16_t bf16x2 __attribute__((ext_vector_type(2)));
typedef float f32x4 __attribute__((ext_vector_type(4)));

constexpr int L = 1024;
constexpr int H = 8;
constexpr int E = 64;
constexpr int HE = H * E;   // 512
constexpr int TM = 32;      // l-tile rows per block
constexpr int NT = 16;      // s-tiles of 64

__device__ __forceinline__ float rcp_fast(float x) { return __builtin_amdgcn_rcpf(x); }
__device__ __forceinline__ float tanh_fast(float x) {
  return 1.0f - 2.0f * rcp_fast(__expf(2.0f * x) + 1.0f);
}
__device__ __forceinline__ float sigm_fast(float x) {
  return rcp_fast(1.0f + __expf(-x));
}

__device__ __forceinline__ f32x4 mfma16(bf16x8 a, bf16x8 b, f32x4 c) {
  return __builtin_amdgcn_mfma_f32_16x16x32_bf16(a, b, c, 0, 0, 0);
}

// split fp32 -> hi bf16 + lo bf16 (residual), store 4 of each (8B writes)
__device__ __forceinline__ void split_store(bf16_t* hi, bf16_t* lo, float4 x) {
  bf16x4 hv, lv;
  hv[0] = (bf16_t)x.x; lv[0] = (bf16_t)(x.x - (float)hv[0]);
  hv[1] = (bf16_t)x.y; lv[1] = (bf16_t)(x.y - (float)hv[1]);
  hv[2] = (bf16_t)x.z; lv[2] = (bf16_t)(x.z - (float)hv[2]);
  hv[3] = (bf16_t)x.w; lv[3] = (bf16_t)(x.w - (float)hv[3]);
  *(bf16x4*)hi = hv;
  *(bf16x4*)lo = lv;
}

// Fused: dual QK^T (bf16x3 split MFMA) -> transform -> att store + entropy
//        -> PV (bf16 MFMA). Block = 128 thr (2 waves), each wave owns 16 l-rows.
// grid (L/TM = 32, BH = 16)
__global__ __launch_bounds__(128, 1) void fused_attn(
    const float* __restrict__ q, const float* __restrict__ kk,
    const float* __restrict__ v,
    float* __restrict__ Vout, float* __restrict__ attg, float* __restrict__ entr,
    const float* __restrict__ p_lgg, const float* __restrict__ p_ltg,
    const float* __restrict__ p_lgd, const float* __restrict__ p_ltd)
{
  // LDS (stride 72 bf16 keeps 16B alignment for b128 frag reads + spreads banks)
  __shared__ bf16_t Qa_hi[TM][72], Qa_lo[TM][72];   // Q l-tile planes [l][e]
  __shared__ bf16_t Ka_hi[TM][72], Ka_lo[TM][72];   // K l-tile planes [l][e]
  __shared__ bf16_t KQ_hi[64][72], KQ_lo[64][72];   // s-tile K then Q [s][e]
  __shared__ bf16_t Vt[64][72];                     // V transposed [e][s]
  __shared__ float  T2ex[2][64][17];                // per-wave T2 exchange [s][l]
  __shared__ bf16_t attL[2][16][72];                // per-wave att strip [l][s]

  const int tid = threadIdx.x;
  const int w = tid >> 6;        // wave 0/1
  const int lane = tid & 63;
  const int c = lane & 15;       // MFMA n-lane / A-row lane
  const int qd = lane >> 4;      // quad
  const int t8 = tid >> 4;       // 0..7 (staging row group)
  const int c4 = tid & 15;
  const int lt = blockIdx.x;
  const int bh = blockIdx.y;
  const int b = bh >> 3, h = bh & 7;
  const int l0 = lt * TM;

  const float gg = fminf(fmaxf(__expf(p_lgg[0]), 1e-3f), 20.0f);
  const float tg = fminf(fmaxf(__expf(p_ltg[0]), 1e-3f), 10.0f);
  const float gd = fminf(fmaxf(__expf(p_lgd[0]), 1e-3f), 20.0f);
  const float td = fminf(fmaxf(__expf(p_ltd[0]), 1e-3f), 10.0f);
  const float inv_tg = 1.0f / tg;
  const float inv_td = 1.0f / td;
  const float gd_inv_td = gd * inv_td;

  const float* qlbase = q  + ((size_t)(b * L + l0) * H + h) * E;  // l-rows
  const float* qsbase = q  + ((size_t)b * L * H + h) * E;         // s-rows
  const float* kbase  = kk + ((size_t)b * L * H + h) * E;
  const float* vbase  = v  + ((size_t)b * L * H + h) * E;

  // ---- prologue: stage Qa/Ka hi/lo planes (32 rows) ----
#pragma unroll
  for (int i = 0; i < 4; ++i) {
    int r = t8 + 8 * i;  // 0..31
    float4 qa = *(const float4*)(qlbase + (size_t)r * HE + c4 * 4);
    float4 ka = *(const float4*)(kbase + (size_t)(l0 + r) * HE + c4 * 4);
    split_store(&Qa_hi[r][c4 * 4], &Qa_lo[r][c4 * 4], qa);
    split_store(&Ka_hi[r][c4 * 4], &Ka_lo[r][c4 * 4], ka);
  }

  // ---- prefetch s-tile 0 into registers ----
  float4 kpre[8], qpre[8];
  float vpre[32];
#pragma unroll
  for (int i = 0; i < 8; ++i)
    kpre[i] = *(const float4*)(kbase + (size_t)(t8 + 8 * i) * HE + c4 * 4);
#pragma unroll
  for (int i = 0; i < 8; ++i)
    qpre[i] = *(const float4*)(qsbase + (size_t)(t8 + 8 * i) * HE + c4 * 4);
#pragma unroll
  for (int j = 0; j < 32; ++j)
    vpre[j] = vbase[(size_t)(w * 32 + j) * HE + lane];

  __syncthreads();

  // preload Qa/Ka fragments (constant across s-tiles)
  bf16x8 qaf[2][2], kaf[2][2];  // [kstep][hi=0/lo=1]
#pragma unroll
  for (int ks = 0; ks < 2; ++ks) {
    qaf[ks][0] = *(const bf16x8*)&Qa_hi[w * 16 + c][ks * 32 + qd * 8];
    qaf[ks][1] = *(const bf16x8*)&Qa_lo[w * 16 + c][ks * 32 + qd * 8];
    kaf[ks][0] = *(const bf16x8*)&Ka_hi[w * 16 + c][ks * 32 + qd * 8];
    kaf[ks][1] = *(const bf16x8*)&Ka_lo[w * 16 + c][ks * 32 + qd * 8];
  }

  f32x4 accv[4] = {};
  float ent[4] = {0.f, 0.f, 0.f, 0.f};
  const int gl_base = l0 + w * 16 + qd * 4;

  for (int it = 0; it < NT; ++it) {
    const int s0 = it * 64;
    const int snext = ((it + 1) & 15) * 64;

    __syncthreads();  // prior-iter KQ/Vt/attL reads complete
    // phase A: write K s-tile planes + Vt
#pragma unroll
    for (int i = 0; i < 8; ++i) {
      int r = t8 + 8 * i;
      split_store(&KQ_hi[r][c4 * 4], &KQ_lo[r][c4 * 4], kpre[i]);
    }
#pragma unroll
    for (int j = 0; j < 16; ++j) {
      bf16x2 p;
      p[0] = (bf16_t)vpre[2 * j];
      p[1] = (bf16_t)vpre[2 * j + 1];
      *(bf16x2*)&Vt[lane][w * 32 + 2 * j] = p;
    }
    __syncthreads();

    // prefetch next K,V
#pragma unroll
    for (int i = 0; i < 8; ++i)
      kpre[i] = *(const float4*)(kbase + (size_t)(snext + t8 + 8 * i) * HE + c4 * 4);
#pragma unroll
    for (int j = 0; j < 32; ++j)
      vpre[j] = vbase[(size_t)(snext + w * 32 + j) * HE + lane];

    // T1: scores(l, s) = Q[l]·K[s]  (hi*hi + hi*lo + lo*hi)
    f32x4 acc1[4] = {};
#pragma unroll
    for (int nt = 0; nt < 4; ++nt) {
#pragma unroll
      for (int ks = 0; ks < 2; ++ks) {
        bf16x8 bhv = *(const bf16x8*)&KQ_hi[nt * 16 + c][ks * 32 + qd * 8];
        bf16x8 blv = *(const bf16x8*)&KQ_lo[nt * 16 + c][ks * 32 + qd * 8];
        acc1[nt] = mfma16(qaf[ks][0], bhv, acc1[nt]);
        acc1[nt] = mfma16(qaf[ks][0], blv, acc1[nt]);
        acc1[nt] = mfma16(qaf[ks][1], bhv, acc1[nt]);
      }
    }
    __syncthreads();  // T1 reads of KQ done

    // phase B: overwrite KQ with Q s-tile planes
#pragma unroll
    for (int i = 0; i < 8; ++i) {
      int r = t8 + 8 * i;
      split_store(&KQ_hi[r][c4 * 4], &KQ_lo[r][c4 * 4], qpre[i]);
    }
    __syncthreads();

    // prefetch next Q
#pragma unroll
    for (int i = 0; i < 8; ++i)
      qpre[i] = *(const float4*)(qsbase + (size_t)(snext + t8 + 8 * i) * HE + c4 * 4);

    // T2: scores(s, l) = Q[s]·K[l]  (same product order as T1 -> diag exact 0)
    f32x4 acc2[4] = {};
#pragma unroll
    for (int mt = 0; mt < 4; ++mt) {
#pragma unroll
      for (int ks = 0; ks < 2; ++ks) {
        bf16x8 ahv = *(const bf16x8*)&KQ_hi[mt * 16 + c][ks * 32 + qd * 8];
        bf16x8 alv = *(const bf16x8*)&KQ_lo[mt * 16 + c][ks * 32 + qd * 8];
        acc2[mt] = mfma16(ahv, kaf[ks][0], acc2[mt]);
        acc2[mt] = mfma16(ahv, kaf[ks][1], acc2[mt]);
        acc2[mt] = mfma16(alv, kaf[ks][0], acc2[mt]);
      }
    }

    // T2 exchange: C-layout (row=s, col=l) -> LDS [s][l]
#pragma unroll
    for (int mt = 0; mt < 4; ++mt)
#pragma unroll
      for (int r = 0; r < 4; ++r)
        T2ex[w][mt * 16 + qd * 4 + r][c] = acc2[mt][r];
    __syncthreads();

    // transform + entropy + att store + attL
    float* attrow0 = attg + ((size_t)bh * L + gl_base) * L + s0;
#pragma unroll
    for (int nt = 0; nt < 4; ++nt) {
#pragma unroll
      for (int r = 0; r < 4; ++r) {
        float x = 0.125f * acc1[nt][r];                    // scores(l,s)
        float y = 0.125f * T2ex[w][nt * 16 + c][qd * 4 + r];  // scores(s,l)
        float Ss = 0.5f * (x + y);
        float Aa = 0.5f * (x - y);
        float gate = sigm_fast(gg * tanh_fast(Ss * inv_tg));
        float dir  = sigm_fast(gd * tanh_fast(Aa * inv_td));
        float t    = tanh_fast(Aa * gd_inv_td);
        float a = fmaxf(t, 0.0f) * gate * dir;
        ent[r] -= a * __logf(fmaxf(a, 1e-8f));
        attrow0[(size_t)r * L + nt * 16 + c] = a;
        attL[w][qd * 4 + r][nt * 16 + c] = (bf16_t)a;
      }
    }
    __syncthreads();  // attL visible (cross-lane within wave)

    // PV: accv += att (A, bf16) x V (B, bf16)
#pragma unroll
    for (int ks = 0; ks < 2; ++ks) {
      bf16x8 af = *(const bf16x8*)&attL[w][c][ks * 32 + qd * 8];
#pragma unroll
      for (int ne = 0; ne < 4; ++ne) {
        bf16x8 bfv = *(const bf16x8*)&Vt[ne * 16 + c][ks * 32 + qd * 8];
        accv[ne] = mfma16(af, bfv, accv[ne]);
      }
    }
  }

  // epilogue: V out + entropy
#pragma unroll
  for (int r = 0; r < 4; ++r) {
    float* vb = Vout + ((size_t)(b * L + gl_base + r) * H + h) * E;
#pragma unroll
    for (int ne = 0; ne < 4; ++ne) vb[ne * 16 + c] = accv[ne][r];
    float e4 = ent[r];
    e4 += __shfl_xor(e4, 1);
    e4 += __shfl_xor(e4, 2);
    e4 += __shfl_xor(e4, 4);
    e4 += __shfl_xor(e4, 8);
    if (c == 0) entr[(size_t)bh * L + gl_base + r] = e4;
  }
}

}  // namespace

extern "C" void kernel_launch(void* const* d_in, const int* in_sizes, int n_in,
                              void* d_out, int out_size, void* d_ws, size_t ws_size,
                              hipStream_t stream) {
  const float* q = (const float*)d_in[0];
  const float* k = (const float*)d_in[1];
  const float* v = (const float*)d_in[2];
  const float* p_lgg = (const float*)d_in[7];
  const float* p_ltg = (const float*)d_in[8];
  const float* p_lgd = (const float*)d_in[9];
  const float* p_ltd = (const float*)d_in[10];

  float* Vout = (float*)d_out;          // (B,L,H,E)   1,048,576
  float* att  = Vout + 1048576;         // (B,H,L,S)  16,777,216
  float* entr = att + 16777216;         // (B,H,L)        16,384

  fused_attn<<<dim3(L / TM, 16), 128, 0, stream>>>(
      q, k, v, Vout, att, entr, p_lgg, p_ltg, p_lgd, p_ltd);
}

// Round 4
// 150.754 us; speedup vs baseline: 1.5149x; 1.1488x over previous
//
#include <hip/hip_runtime.h>
#include <math.h>

namespace {

typedef __bf16 bf16_t;
typedef bf16_t bf16x8 __attribute__((ext_vector_type(8)));
typedef bf16_t bf16x4 __attribute__((ext_vector_type(4)));
typedef bf16_t bf16x2 __attribute__((ext_vector_type(2)));
typedef float f32x4 __attribute__((ext_vector_type(4)));

constexpr int L = 1024;
constexpr int H = 8;
constexpr int E = 64;
constexpr int HE = H * E;            // 512
constexpr int BH = 16;
constexpr size_t PL = (size_t)BH * L * E;  // 1,048,576 elems per plane

__device__ __forceinline__ float rcp_fast(float x) { return __builtin_amdgcn_rcpf(x); }
__device__ __forceinline__ float tanh_fast(float x) {
  return 1.0f - 2.0f * rcp_fast(__expf(2.0f * x) + 1.0f);
}
__device__ __forceinline__ float sigm_fast(float x) {
  return rcp_fast(1.0f + __expf(-x));
}
__device__ __forceinline__ f32x4 mfma16(bf16x8 a, bf16x8 b, f32x4 c) {
  return __builtin_amdgcn_mfma_f32_16x16x32_bf16(a, b, c, 0, 0, 0);
}
__device__ __forceinline__ void split4(float4 x, bf16x4& hv, bf16x4& lv) {
  hv[0] = (bf16_t)x.x; lv[0] = (bf16_t)(x.x - (float)hv[0]);
  hv[1] = (bf16_t)x.y; lv[1] = (bf16_t)(x.y - (float)hv[1]);
  hv[2] = (bf16_t)x.z; lv[2] = (bf16_t)(x.z - (float)hv[2]);
  hv[3] = (bf16_t)x.w; lv[3] = (bf16_t)(x.w - (float)hv[3]);
}

// ===========================================================================
// Prep: Q,K -> bf16 hi/lo planes [bh][l][e]; V -> VT bf16 [bh][e][s].
// grid (16 bh x 8 l-chunks) = 128 blocks, 256 thr.
// ===========================================================================
__global__ __launch_bounds__(256) void k_prep(
    const float* __restrict__ q, const float* __restrict__ k,
    const float* __restrict__ v, bf16_t* __restrict__ ws)
{
  bf16_t* Qh = ws;
  bf16_t* Ql = ws + PL;
  bf16_t* Kh = ws + 2 * PL;
  bf16_t* Kl = ws + 3 * PL;
  bf16_t* VT = ws + 4 * PL;
  const int bh = blockIdx.x >> 3, chunk = blockIdx.x & 7;
  const int b = bh >> 3, h = bh & 7;
  const int tid = threadIdx.x, t8 = tid >> 4, c4 = tid & 15;
  __shared__ bf16_t Vb[64][136];  // [e][l-local 128]

#pragma unroll
  for (int pass = 0; pass < 8; ++pass) {
    const int row = chunk * 128 + pass * 16 + t8;
    const size_t gin = ((size_t)(b * L + row) * H + h) * E + c4 * 4;
    const size_t gout = ((size_t)bh * L + row) * E + c4 * 4;
    float4 q4 = *(const float4*)(q + gin);
    float4 k4 = *(const float4*)(k + gin);
    float4 v4 = *(const float4*)(v + gin);
    bf16x4 hv, lv;
    split4(q4, hv, lv);
    *(bf16x4*)(Qh + gout) = hv; *(bf16x4*)(Ql + gout) = lv;
    split4(k4, hv, lv);
    *(bf16x4*)(Kh + gout) = hv; *(bf16x4*)(Kl + gout) = lv;
    const int sl = pass * 16 + t8;
    Vb[c4 * 4 + 0][sl] = (bf16_t)v4.x;
    Vb[c4 * 4 + 1][sl] = (bf16_t)v4.y;
    Vb[c4 * 4 + 2][sl] = (bf16_t)v4.z;
    Vb[c4 * 4 + 3][sl] = (bf16_t)v4.w;
  }
  __syncthreads();
#pragma unroll
  for (int pass = 0; pass < 4; ++pass) {
    const int idx = pass * 256 + tid;
    const int e = idx >> 4, ch = idx & 15;
    bf16x8 val = *(const bf16x8*)&Vb[e][ch * 8];
    *(bf16x8*)(VT + ((size_t)bh * E + e) * L + chunk * 128 + ch * 8) = val;
  }
}

// ===========================================================================
// Zero-init Vout (1M floats) + entr (16K floats). grid 1040 x 256.
// ===========================================================================
__global__ __launch_bounds__(256) void k_zero(float* __restrict__ Vout,
                                              float* __restrict__ entr)
{
  const int idx = blockIdx.x * 256 + threadIdx.x;
  const float4 z = make_float4(0.f, 0.f, 0.f, 0.f);
  if (idx < 262144) *(float4*)(Vout + (size_t)idx * 4) = z;
  else              *(float4*)(entr + (size_t)(idx - 262144) * 4) = z;
}

// ===========================================================================
// Main fused kernel. grid (32 lt, 16 bh, 2 s-split), 256 thr (4 waves).
// Wave w: l-half (w&1)*16 rows, s-half (w>>1)*32 of each 64-s-tile.
// Staging: each thread owns rows tid>>2, 16-col slot (tid&3)*16, covered by
// TWO bf16x8 (16 elems = 32 B) per plane — the R3 bug was loading only one.
// __launch_bounds__(256,3): prefetch regs ~40; (256,4)'s 128-VGPR cap spills.
// ===========================================================================
__global__ __launch_bounds__(256, 3) void k_main(
    const bf16_t* __restrict__ ws,
    float* __restrict__ Vout, float* __restrict__ attg, float* __restrict__ entr,
    const float* __restrict__ p_lgg, const float* __restrict__ p_ltg,
    const float* __restrict__ p_lgd, const float* __restrict__ p_ltd)
{
  const bf16_t* Qh = ws;
  const bf16_t* Ql = ws + PL;
  const bf16_t* Kh = ws + 2 * PL;
  const bf16_t* Kl = ws + 3 * PL;
  const bf16_t* VT = ws + 4 * PL;

  __shared__ __align__(16) char smem[32768];
  bf16_t (*KQh)[72]  = (bf16_t(*)[72])(smem);            //  9216 B
  bf16_t (*KQl)[72]  = (bf16_t(*)[72])(smem + 9216);     //  9216 B
  bf16_t (*Vt)[72]   = (bf16_t(*)[72])(smem + 18432);    //  9216 B
  bf16_t (*attL)[40] = (bf16_t(*)[40])(smem + 27648);    //  5120 B ([64][40])

  const int tid = threadIdx.x;
  const int w = tid >> 6, lane = tid & 63;
  const int c = lane & 15, qd = lane >> 4;
  const int lh = w & 1, sh = w >> 1;
  const int lt = blockIdx.x, bh = blockIdx.y, zb = blockIdx.z;
  const int b = bh >> 3, h = bh & 7;
  const int l0 = lt * 32;

  const float gg = fminf(fmaxf(__expf(p_lgg[0]), 1e-3f), 20.0f);
  const float tg = fminf(fmaxf(__expf(p_ltg[0]), 1e-3f), 10.0f);
  const float gd = fminf(fmaxf(__expf(p_lgd[0]), 1e-3f), 20.0f);
  const float td = fminf(fmaxf(__expf(p_ltd[0]), 1e-3f), 10.0f);
  const float inv_tg = 1.0f / tg;
  const float inv_td = 1.0f / td;
  const float gd_inv_td = gd * inv_td;

  // A-fragments (held all loop): Q/K hi+lo rows l0 + lh*16 + c, from global
  bf16x8 qaf[2][2], kaf[2][2];
  {
    const size_t aro = ((size_t)bh * L + l0 + lh * 16 + c) * E;
#pragma unroll
    for (int ks = 0; ks < 2; ++ks) {
      qaf[ks][0] = *(const bf16x8*)(Qh + aro + ks * 32 + qd * 8);
      qaf[ks][1] = *(const bf16x8*)(Ql + aro + ks * 32 + qd * 8);
      kaf[ks][0] = *(const bf16x8*)(Kh + aro + ks * 32 + qd * 8);
      kaf[ks][1] = *(const bf16x8*)(Kl + aro + ks * 32 + qd * 8);
    }
  }

  // staging slot: row tid>>2, columns (tid&3)*16 .. +15  (two bf16x8)
  const int srow = tid >> 2, scol = (tid & 3) * 16;

  bf16x8 kh8a, kh8b, kl8a, kl8b, vt8a, vt8b, qh8a, qh8b, ql8a, ql8b;
  {
    const int s0 = zb * 8 * 64;
    const size_t off = ((size_t)bh * L + s0 + srow) * E + scol;
    kh8a = *(const bf16x8*)(Kh + off);
    kh8b = *(const bf16x8*)(Kh + off + 8);
    kl8a = *(const bf16x8*)(Kl + off);
    kl8b = *(const bf16x8*)(Kl + off + 8);
    const size_t voff = ((size_t)bh * E + srow) * L + s0 + scol;
    vt8a = *(const bf16x8*)(VT + voff);
    vt8b = *(const bf16x8*)(VT + voff + 8);
  }

  f32x4 accv[4] = {};
  float ent[4] = {0.f, 0.f, 0.f, 0.f};

  for (int it = 0; it < 8; ++it) {
    const int ti = zb * 8 + it;
    const int s0 = ti * 64;
    const int s0n = ((ti + 1) & 15) * 64;

    __syncthreads();  // prior-iter T2/PV LDS reads done
    *(bf16x8*)&KQh[srow][scol]     = kh8a;
    *(bf16x8*)&KQh[srow][scol + 8] = kh8b;
    *(bf16x8*)&KQl[srow][scol]     = kl8a;
    *(bf16x8*)&KQl[srow][scol + 8] = kl8b;
    *(bf16x8*)&Vt[srow][scol]      = vt8a;
    *(bf16x8*)&Vt[srow][scol + 8]  = vt8b;
    // prefetch Q s-tile (used in phase B)
    {
      const size_t off = ((size_t)bh * L + s0 + srow) * E + scol;
      qh8a = *(const bf16x8*)(Qh + off);
      qh8b = *(const bf16x8*)(Qh + off + 8);
      ql8a = *(const bf16x8*)(Ql + off);
      ql8b = *(const bf16x8*)(Ql + off + 8);
    }
    __syncthreads();

    // T1: D1[l][s] = Q[l]·K[s]   (order: qh·kh, qh·kl, ql·kh)
    f32x4 acc1[2] = {}, acc2[2] = {};
#pragma unroll
    for (int nt = 0; nt < 2; ++nt) {
      const int brow = sh * 32 + nt * 16 + c;
#pragma unroll
      for (int ks = 0; ks < 2; ++ks) {
        bf16x8 bhv = *(const bf16x8*)&KQh[brow][ks * 32 + qd * 8];
        bf16x8 blv = *(const bf16x8*)&KQl[brow][ks * 32 + qd * 8];
        acc1[nt] = mfma16(qaf[ks][0], bhv, acc1[nt]);
        acc1[nt] = mfma16(qaf[ks][0], blv, acc1[nt]);
        acc1[nt] = mfma16(qaf[ks][1], bhv, acc1[nt]);
      }
    }
    __syncthreads();  // T1 reads done

    // phase B: overwrite KQ with Q s-tile planes
    *(bf16x8*)&KQh[srow][scol]     = qh8a;
    *(bf16x8*)&KQh[srow][scol + 8] = qh8b;
    *(bf16x8*)&KQl[srow][scol]     = ql8a;
    *(bf16x8*)&KQl[srow][scol + 8] = ql8b;
    // prefetch next iteration's K + VT tiles
    {
      const size_t off = ((size_t)bh * L + s0n + srow) * E + scol;
      kh8a = *(const bf16x8*)(Kh + off);
      kh8b = *(const bf16x8*)(Kh + off + 8);
      kl8a = *(const bf16x8*)(Kl + off);
      kl8b = *(const bf16x8*)(Kl + off + 8);
      const size_t voff = ((size_t)bh * E + srow) * L + s0n + scol;
      vt8a = *(const bf16x8*)(VT + voff);
      vt8b = *(const bf16x8*)(VT + voff + 8);
    }
    __syncthreads();

    // T2: D2[l][s] = K[l]·Q[s]   (order: kh·qh, kl·qh, kh·ql — matches T1
    // term values at the diagonal -> Aa bitwise 0 -> att diag exactly 0)
#pragma unroll
    for (int nt = 0; nt < 2; ++nt) {
      const int brow = sh * 32 + nt * 16 + c;
#pragma unroll
      for (int ks = 0; ks < 2; ++ks) {
        bf16x8 qbh = *(const bf16x8*)&KQh[brow][ks * 32 + qd * 8];
        bf16x8 qbl = *(const bf16x8*)&KQl[brow][ks * 32 + qd * 8];
        acc2[nt] = mfma16(kaf[ks][0], qbh, acc2[nt]);
        acc2[nt] = mfma16(kaf[ks][1], qbh, acc2[nt]);
        acc2[nt] = mfma16(kaf[ks][0], qbl, acc2[nt]);
      }
    }

    // transform (register-local), att store, attL, entropy
    float* arow = attg + ((size_t)bh * L + l0 + lh * 16 + qd * 4) * L + s0 + sh * 32;
#pragma unroll
    for (int nt = 0; nt < 2; ++nt) {
#pragma unroll
      for (int r = 0; r < 4; ++r) {
        float x = 0.125f * acc1[nt][r];
        float y = 0.125f * acc2[nt][r];
        float Ss = 0.5f * (x + y);
        float Aa = 0.5f * (x - y);
        float gate = sigm_fast(gg * tanh_fast(Ss * inv_tg));
        float dir  = sigm_fast(gd * tanh_fast(Aa * inv_td));
        float t    = tanh_fast(Aa * gd_inv_td);
        float a = fmaxf(t, 0.0f) * gate * dir;
        ent[r] -= a * __logf(fmaxf(a, 1e-8f));
        arow[(size_t)r * L + nt * 16 + c] = a;
        attL[w * 16 + qd * 4 + r][nt * 16 + c] = (bf16_t)a;
      }
    }
    // wave-local D-layout -> A-layout exchange: fence (lgkm drain + compiler
    // order) is sufficient — no cross-wave sharing of attL rows.
    __threadfence_block();

    // PV
    bf16x8 af = *(const bf16x8*)&attL[w * 16 + c][qd * 8];
#pragma unroll
    for (int ne = 0; ne < 4; ++ne) {
      bf16x8 bv = *(const bf16x8*)&Vt[ne * 16 + c][sh * 32 + qd * 8];
      accv[ne] = mfma16(af, bv, accv[ne]);
    }
  }

  // ---- epilogue: combine s-halves, atomic into global (s-split blocks) ----
  __syncthreads();
  float* red = (float*)smem;  // [2][16][68] f32, aliases KQh (dead)
  if (sh == 1) {
#pragma unroll
    for (int ne = 0; ne < 4; ++ne)
#pragma unroll
      for (int r = 0; r < 4; ++r)
        red[((size_t)lh * 16 + qd * 4 + r) * 68 + ne * 16 + c] = accv[ne][r];
  }
  __syncthreads();
  if (sh == 0) {
#pragma unroll
    for (int ne = 0; ne < 4; ++ne)
#pragma unroll
      for (int r = 0; r < 4; ++r) {
        float val = accv[ne][r] +
                    red[((size_t)lh * 16 + qd * 4 + r) * 68 + ne * 16 + c];
        atomicAdd(Vout + ((size_t)(b * L + l0 + lh * 16 + qd * 4 + r) * H + h) * E +
                      ne * 16 + c,
                  val);
      }
  }
#pragma unroll
  for (int r = 0; r < 4; ++r) {
    float e = ent[r];
    e += __shfl_xor(e, 1);
    e += __shfl_xor(e, 2);
    e += __shfl_xor(e, 4);
    e += __shfl_xor(e, 8);
    if (c == 0)
      atomicAdd(entr + (size_t)bh * L + l0 + lh * 16 + qd * 4 + r, e);
  }
}

// ===========================================================================
// Fallback (R2 kernel) if ws_size is too small for the planes.
// ===========================================================================
__device__ __forceinline__ void split_store(bf16_t* hi, bf16_t* lo, float4 x) {
  bf16x4 hv, lv;
  split4(x, hv, lv);
  *(bf16x4*)hi = hv;
  *(bf16x4*)lo = lv;
}

__global__ __launch_bounds__(128, 1) void fused_attn(
    const float* __restrict__ q, const float* __restrict__ kk,
    const float* __restrict__ v,
    float* __restrict__ Vout, float* __restrict__ attg, float* __restrict__ entr,
    const float* __restrict__ p_lgg, const float* __restrict__ p_ltg,
    const float* __restrict__ p_lgd, const float* __restrict__ p_ltd)
{
  constexpr int TM = 32;
  __shared__ bf16_t Qa_hi[TM][72], Qa_lo[TM][72];
  __shared__ bf16_t Ka_hi[TM][72], Ka_lo[TM][72];
  __shared__ bf16_t KQ_hi[64][72], KQ_lo[64][72];
  __shared__ bf16_t Vts[64][72];
  __shared__ float  T2ex[2][64][17];
  __shared__ bf16_t attLs[2][16][72];

  const int tid = threadIdx.x;
  const int w = tid >> 6;
  const int lane = tid & 63;
  const int c = lane & 15;
  const int qd = lane >> 4;
  const int t8 = tid >> 4;
  const int c4 = tid & 15;
  const int lt = blockIdx.x;
  const int bh = blockIdx.y;
  const int b = bh >> 3, h = bh & 7;
  const int l0 = lt * TM;

  const float gg = fminf(fmaxf(__expf(p_lgg[0]), 1e-3f), 20.0f);
  const float tg = fminf(fmaxf(__expf(p_ltg[0]), 1e-3f), 10.0f);
  const float gd = fminf(fmaxf(__expf(p_lgd[0]), 1e-3f), 20.0f);
  const float td = fminf(fmaxf(__expf(p_ltd[0]), 1e-3f), 10.0f);
  const float inv_tg = 1.0f / tg;
  const float inv_td = 1.0f / td;
  const float gd_inv_td = gd * inv_td;

  const float* qlbase = q  + ((size_t)(b * L + l0) * H + h) * E;
  const float* qsbase = q  + ((size_t)b * L * H + h) * E;
  const float* kbase  = kk + ((size_t)b * L * H + h) * E;
  const float* vbase  = v  + ((size_t)b * L * H + h) * E;

#pragma unroll
  for (int i = 0; i < 4; ++i) {
    int r = t8 + 8 * i;
    float4 qa = *(const float4*)(qlbase + (size_t)r * HE + c4 * 4);
    float4 ka = *(const float4*)(kbase + (size_t)(l0 + r) * HE + c4 * 4);
    split_store(&Qa_hi[r][c4 * 4], &Qa_lo[r][c4 * 4], qa);
    split_store(&Ka_hi[r][c4 * 4], &Ka_lo[r][c4 * 4], ka);
  }

  float4 kpre[8], qpre[8];
  float vpre[32];
#pragma unroll
  for (int i = 0; i < 8; ++i)
    kpre[i] = *(const float4*)(kbase + (size_t)(t8 + 8 * i) * HE + c4 * 4);
#pragma unroll
  for (int i = 0; i < 8; ++i)
    qpre[i] = *(const float4*)(qsbase + (size_t)(t8 + 8 * i) * HE + c4 * 4);
#pragma unroll
  for (int j = 0; j < 32; ++j)
    vpre[j] = vbase[(size_t)(w * 32 + j) * HE + lane];

  __syncthreads();

  bf16x8 qaf[2][2], kaf[2][2];
#pragma unroll
  for (int ks = 0; ks < 2; ++ks) {
    qaf[ks][0] = *(const bf16x8*)&Qa_hi[w * 16 + c][ks * 32 + qd * 8];
    qaf[ks][1] = *(const bf16x8*)&Qa_lo[w * 16 + c][ks * 32 + qd * 8];
    kaf[ks][0] = *(const bf16x8*)&Ka_hi[w * 16 + c][ks * 32 + qd * 8];
    kaf[ks][1] = *(const bf16x8*)&Ka_lo[w * 16 + c][ks * 32 + qd * 8];
  }

  f32x4 accv[4] = {};
  float ent[4] = {0.f, 0.f, 0.f, 0.f};
  const int gl_base = l0 + w * 16 + qd * 4;

  for (int it = 0; it < 16; ++it) {
    const int s0 = it * 64;
    const int snext = ((it + 1) & 15) * 64;

    __syncthreads();
#pragma unroll
    for (int i = 0; i < 8; ++i) {
      int r = t8 + 8 * i;
      split_store(&KQ_hi[r][c4 * 4], &KQ_lo[r][c4 * 4], kpre[i]);
    }
#pragma unroll
    for (int j = 0; j < 16; ++j) {
      bf16x2 p;
      p[0] = (bf16_t)vpre[2 * j];
      p[1] = (bf16_t)vpre[2 * j + 1];
      *(bf16x2*)&Vts[lane][w * 32 + 2 * j] = p;
    }
    __syncthreads();

#pragma unroll
    for (int i = 0; i < 8; ++i)
      kpre[i] = *(const float4*)(kbase + (size_t)(snext + t8 + 8 * i) * HE + c4 * 4);
#pragma unroll
    for (int j = 0; j < 32; ++j)
      vpre[j] = vbase[(size_t)(snext + w * 32 + j) * HE + lane];

    f32x4 acc1[4] = {};
#pragma unroll
    for (int nt = 0; nt < 4; ++nt) {
#pragma unroll
      for (int ks = 0; ks < 2; ++ks) {
        bf16x8 bhv = *(const bf16x8*)&KQ_hi[nt * 16 + c][ks * 32 + qd * 8];
        bf16x8 blv = *(const bf16x8*)&KQ_lo[nt * 16 + c][ks * 32 + qd * 8];
        acc1[nt] = mfma16(qaf[ks][0], bhv, acc1[nt]);
        acc1[nt] = mfma16(qaf[ks][0], blv, acc1[nt]);
        acc1[nt] = mfma16(qaf[ks][1], bhv, acc1[nt]);
      }
    }
    __syncthreads();

#pragma unroll
    for (int i = 0; i < 8; ++i) {
      int r = t8 + 8 * i;
      split_store(&KQ_hi[r][c4 * 4], &KQ_lo[r][c4 * 4], qpre[i]);
    }
    __syncthreads();

#pragma unroll
    for (int i = 0; i < 8; ++i)
      qpre[i] = *(const float4*)(qsbase + (size_t)(snext + t8 + 8 * i) * HE + c4 * 4);

    f32x4 acc2[4] = {};
#pragma unroll
    for (int mt = 0; mt < 4; ++mt) {
#pragma unroll
      for (int ks = 0; ks < 2; ++ks) {
        bf16x8 ahv = *(const bf16x8*)&KQ_hi[mt * 16 + c][ks * 32 + qd * 8];
        bf16x8 alv = *(const bf16x8*)&KQ_lo[mt * 16 + c][ks * 32 + qd * 8];
        acc2[mt] = mfma16(ahv, kaf[ks][0], acc2[mt]);
        acc2[mt] = mfma16(ahv, kaf[ks][1], acc2[mt]);
        acc2[mt] = mfma16(alv, kaf[ks][0], acc2[mt]);
      }
    }

#pragma unroll
    for (int mt = 0; mt < 4; ++mt)
#pragma unroll
      for (int r = 0; r < 4; ++r)
        T2ex[w][mt * 16 + qd * 4 + r][c] = acc2[mt][r];
    __syncthreads();

    float* attrow0 = attg + ((size_t)bh * L + gl_base) * L + s0;
#pragma unroll
    for (int nt = 0; nt < 4; ++nt) {
#pragma unroll
      for (int r = 0; r < 4; ++r) {
        float x = 0.125f * acc1[nt][r];
        float y = 0.125f * T2ex[w][nt * 16 + c][qd * 4 + r];
        float Ss = 0.5f * (x + y);
        float Aa = 0.5f * (x - y);
        float gate = sigm_fast(gg * tanh_fast(Ss * inv_tg));
        float dir  = sigm_fast(gd * tanh_fast(Aa * inv_td));
        float t    = tanh_fast(Aa * gd_inv_td);
        float a = fmaxf(t, 0.0f) * gate * dir;
        ent[r] -= a * __logf(fmaxf(a, 1e-8f));
        attrow0[(size_t)r * L + nt * 16 + c] = a;
        attLs[w][qd * 4 + r][nt * 16 + c] = (bf16_t)a;
      }
    }
    __syncthreads();

#pragma unroll
    for (int ks = 0; ks < 2; ++ks) {
      bf16x8 af = *(const bf16x8*)&attLs[w][c][ks * 32 + qd * 8];
#pragma unroll
      for (int ne = 0; ne < 4; ++ne) {
        bf16x8 bfv = *(const bf16x8*)&Vts[ne * 16 + c][ks * 32 + qd * 8];
        accv[ne] = mfma16(af, bfv, accv[ne]);
      }
    }
  }

#pragma unroll
  for (int r = 0; r < 4; ++r) {
    float* vb = Vout + ((size_t)(b * L + gl_base + r) * H + h) * E;
#pragma unroll
    for (int ne = 0; ne < 4; ++ne) vb[ne * 16 + c] = accv[ne][r];
    float e4 = ent[r];
    e4 += __shfl_xor(e4, 1);
    e4 += __shfl_xor(e4, 2);
    e4 += __shfl_xor(e4, 4);
    e4 += __shfl_xor(e4, 8);
    if (c == 0) entr[(size_t)bh * L + gl_base + r] = e4;
  }
}

}  // namespace

extern "C" void kernel_launch(void* const* d_in, const int* in_sizes, int n_in,
                              void* d_out, int out_size, void* d_ws, size_t ws_size,
                              hipStream_t stream) {
  const float* q = (const float*)d_in[0];
  const float* k = (const float*)d_in[1];
  const float* v = (const float*)d_in[2];
  const float* p_lgg = (const float*)d_in[7];
  const float* p_ltg = (const float*)d_in[8];
  const float* p_lgd = (const float*)d_in[9];
  const float* p_ltd = (const float*)d_in[10];

  float* Vout = (float*)d_out;          // (B,L,H,E)   1,048,576
  float* att  = Vout + 1048576;         // (B,H,L,S)  16,777,216
  float* entr = att + 16777216;         // (B,H,L)        16,384

  const size_t need = 5 * PL * sizeof(bf16_t);  // 10,485,760 B
  if (ws_size >= need) {
    bf16_t* ws = (bf16_t*)d_ws;
    k_prep<<<dim3(128), 256, 0, stream>>>(q, k, v, ws);
    k_zero<<<dim3(1040), 256, 0, stream>>>(Vout, entr);
    k_main<<<dim3(32, 16, 2), 256, 0, stream>>>(
        ws, Vout, att, entr, p_lgg, p_ltg, p_lgd, p_ltd);
  } else {
    fused_attn<<<dim3(32, 16), 128, 0, stream>>>(
        q, k, v, Vout, att, entr, p_lgg, p_ltg, p_lgd, p_ltd);
  }
}

// Round 6
// 137.775 us; speedup vs baseline: 1.6576x; 1.0942x over previous
//
#include <hip/hip_runtime.h>
#include <math.h>

namespace {

typedef __bf16 bf16_t;
typedef bf16_t bf16x8 __attribute__((ext_vector_type(8)));
typedef bf16_t bf16x4 __attribute__((ext_vector_type(4)));
typedef bf16_t bf16x2 __attribute__((ext_vector_type(2)));
typedef float f32x4 __attribute__((ext_vector_type(4)));

constexpr int L = 1024;
constexpr int H = 8;
constexpr int E = 64;
constexpr int HE = H * E;            // 512
constexpr int BH = 16;
constexpr size_t PL = (size_t)BH * L * E;  // 1,048,576 elems per plane
constexpr float LOG2E = 1.4426950408889634f;
constexpr float LN2 = 0.6931471805599453f;

__device__ __forceinline__ float rcp_fast(float x) { return __builtin_amdgcn_rcpf(x); }
__device__ __forceinline__ float exp2_fast(float x) { return __builtin_amdgcn_exp2f(x); }
__device__ __forceinline__ float log2_fast(float x) { return __builtin_amdgcn_logf(x); }
__device__ __forceinline__ f32x4 mfma16(bf16x8 a, bf16x8 b, f32x4 c) {
  return __builtin_amdgcn_mfma_f32_16x16x32_bf16(a, b, c, 0, 0, 0);
}
__device__ __forceinline__ void split4(float4 x, bf16x4& hv, bf16x4& lv) {
  hv[0] = (bf16_t)x.x; lv[0] = (bf16_t)(x.x - (float)hv[0]);
  hv[1] = (bf16_t)x.y; lv[1] = (bf16_t)(x.y - (float)hv[1]);
  hv[2] = (bf16_t)x.z; lv[2] = (bf16_t)(x.z - (float)hv[2]);
  hv[3] = (bf16_t)x.w; lv[3] = (bf16_t)(x.w - (float)hv[3]);
}

// ===========================================================================
// Prep + zero-init fused. Blocks [0,256): Q,K -> bf16 hi/lo planes
// [bh][l][e], V -> VT bf16 [bh][e][s] (16 bh x 16 l-chunks of 64).
// Blocks [256,1296): zero Vout (1M f32) + entr (16K f32).
// ===========================================================================
__global__ __launch_bounds__(256) void k_prep(
    const float* __restrict__ q, const float* __restrict__ k,
    const float* __restrict__ v, bf16_t* __restrict__ ws,
    float* __restrict__ Vout, float* __restrict__ entr)
{
  const int bid = blockIdx.x;
  if (bid >= 256) {  // zero-init branch
    const int idx = (bid - 256) * 256 + threadIdx.x;
    const float4 z = make_float4(0.f, 0.f, 0.f, 0.f);
    if (idx < 262144) *(float4*)(Vout + (size_t)idx * 4) = z;
    else              *(float4*)(entr + (size_t)(idx - 262144) * 4) = z;
    return;
  }
  bf16_t* Qh = ws;
  bf16_t* Ql = ws + PL;
  bf16_t* Kh = ws + 2 * PL;
  bf16_t* Kl = ws + 3 * PL;
  bf16_t* VT = ws + 4 * PL;
  const int bh = bid >> 4, chunk = bid & 15;   // 64-row chunks
  const int b = bh >> 3, h = bh & 7;
  const int tid = threadIdx.x, t8 = tid >> 4, c4 = tid & 15;
  __shared__ bf16_t Vb[64][72];  // [e][l-local 64]

#pragma unroll
  for (int pass = 0; pass < 4; ++pass) {
    const int row = chunk * 64 + pass * 16 + t8;
    const size_t gin = ((size_t)(b * L + row) * H + h) * E + c4 * 4;
    const size_t gout = ((size_t)bh * L + row) * E + c4 * 4;
    float4 q4 = *(const float4*)(q + gin);
    float4 k4 = *(const float4*)(k + gin);
    float4 v4 = *(const float4*)(v + gin);
    bf16x4 hv, lv;
    split4(q4, hv, lv);
    *(bf16x4*)(Qh + gout) = hv; *(bf16x4*)(Ql + gout) = lv;
    split4(k4, hv, lv);
    *(bf16x4*)(Kh + gout) = hv; *(bf16x4*)(Kl + gout) = lv;
    const int sl = pass * 16 + t8;
    Vb[c4 * 4 + 0][sl] = (bf16_t)v4.x;
    Vb[c4 * 4 + 1][sl] = (bf16_t)v4.y;
    Vb[c4 * 4 + 2][sl] = (bf16_t)v4.z;
    Vb[c4 * 4 + 3][sl] = (bf16_t)v4.w;
  }
  __syncthreads();
#pragma unroll
  for (int pass = 0; pass < 2; ++pass) {
    const int idx = pass * 256 + tid;
    const int e = idx >> 3, ch = idx & 7;
    bf16x8 val = *(const bf16x8*)&Vb[e][ch * 8];
    *(bf16x8*)(VT + ((size_t)bh * E + e) * L + chunk * 64 + ch * 8) = val;
  }
}

// ===========================================================================
// Main fused kernel. grid (32 lt, 16 bh, 4 s-split) = 2048 blocks, 256 thr
// (4 waves). Wave w: l-half (w&1)*16 rows, s-half (w>>1)*32 of each s-tile.
// LDS 32 KB -> 5 blocks/CU; grid 8/CU demanded -> LDS-capped ~20 waves/CU.
// Each block: 4 s-tiles of 64. Partial V/entropy combined via atomics.
// ===========================================================================
__global__ __launch_bounds__(256, 3) void k_main(
    const bf16_t* __restrict__ ws,
    float* __restrict__ Vout, float* __restrict__ attg, float* __restrict__ entr,
    const float* __restrict__ p_lgg, const float* __restrict__ p_ltg,
    const float* __restrict__ p_lgd, const float* __restrict__ p_ltd)
{
  const bf16_t* Qh = ws;
  const bf16_t* Ql = ws + PL;
  const bf16_t* Kh = ws + 2 * PL;
  const bf16_t* Kl = ws + 3 * PL;
  const bf16_t* VT = ws + 4 * PL;

  __shared__ __align__(16) char smem[32768];
  bf16_t (*KQh)[72]  = (bf16_t(*)[72])(smem);            //  9216 B
  bf16_t (*KQl)[72]  = (bf16_t(*)[72])(smem + 9216);     //  9216 B
  bf16_t (*Vt)[72]   = (bf16_t(*)[72])(smem + 18432);    //  9216 B
  bf16_t (*attL)[40] = (bf16_t(*)[40])(smem + 27648);    //  5120 B ([64][40])

  const int tid = threadIdx.x;
  const int w = tid >> 6, lane = tid & 63;
  const int c = lane & 15, qd = lane >> 4;
  const int lh = w & 1, sh = w >> 1;
  const int lt = blockIdx.x, bh = blockIdx.y, zb = blockIdx.z;
  const int b = bh >> 3, h = bh & 7;
  const int l0 = lt * 32;

  const float gg = fminf(fmaxf(__expf(p_lgg[0]), 1e-3f), 20.0f);
  const float tg = fminf(fmaxf(__expf(p_ltg[0]), 1e-3f), 10.0f);
  const float gd = fminf(fmaxf(__expf(p_lgd[0]), 1e-3f), 20.0f);
  const float td = fminf(fmaxf(__expf(p_ltd[0]), 1e-3f), 10.0f);
  // Folded transform coefficients (scores scale 1/8 * symmetrize 1/2 = 1/16,
  // tanh doubling folded): tanh(z) = 1 - 2/(exp2(2*log2e*z)+1);
  // sigm(z) = 1/(1+exp2(-log2e*z))
  const float A1 = 0.125f * (1.0f / tg) * LOG2E;     // (u/16)*(1/tg)*2*log2e
  const float A2 = 0.125f * (1.0f / td) * LOG2E;
  const float A3 = 0.125f * gd * (1.0f / td) * LOG2E;
  const float G1 = -gg * LOG2E;
  const float G2 = -gd * LOG2E;

  // A-fragments (held all loop): Q/K hi+lo rows l0 + lh*16 + c, from global
  bf16x8 qaf[2][2], kaf[2][2];
  {
    const size_t aro = ((size_t)bh * L + l0 + lh * 16 + c) * E;
#pragma unroll
    for (int ks = 0; ks < 2; ++ks) {
      qaf[ks][0] = *(const bf16x8*)(Qh + aro + ks * 32 + qd * 8);
      qaf[ks][1] = *(const bf16x8*)(Ql + aro + ks * 32 + qd * 8);
      kaf[ks][0] = *(const bf16x8*)(Kh + aro + ks * 32 + qd * 8);
      kaf[ks][1] = *(const bf16x8*)(Kl + aro + ks * 32 + qd * 8);
    }
  }

  // staging slot: row tid>>2, columns (tid&3)*16 .. +15  (two bf16x8)
  const int srow = tid >> 2, scol = (tid & 3) * 16;

  bf16x8 kh8a, kh8b, kl8a, kl8b, vt8a, vt8b, qh8a, qh8b, ql8a, ql8b;
  {
    const int s0 = zb * 4 * 64;
    const size_t off = ((size_t)bh * L + s0 + srow) * E + scol;
    kh8a = *(const bf16x8*)(Kh + off);
    kh8b = *(const bf16x8*)(Kh + off + 8);
    kl8a = *(const bf16x8*)(Kl + off);
    kl8b = *(const bf16x8*)(Kl + off + 8);
    const size_t voff = ((size_t)bh * E + srow) * L + s0 + scol;
    vt8a = *(const bf16x8*)(VT + voff);
    vt8b = *(const bf16x8*)(VT + voff + 8);
  }

  f32x4 accv[4] = {};
  float ent[4] = {0.f, 0.f, 0.f, 0.f};  // accumulated in log2 domain

  for (int it = 0; it < 4; ++it) {
    const int ti = zb * 4 + it;
    const int s0 = ti * 64;
    const int s0n = ((ti + 1) & 15) * 64;

    __syncthreads();  // prior-iter T2/PV LDS reads done
    *(bf16x8*)&KQh[srow][scol]     = kh8a;
    *(bf16x8*)&KQh[srow][scol + 8] = kh8b;
    *(bf16x8*)&KQl[srow][scol]     = kl8a;
    *(bf16x8*)&KQl[srow][scol + 8] = kl8b;
    *(bf16x8*)&Vt[srow][scol]      = vt8a;
    *(bf16x8*)&Vt[srow][scol + 8]  = vt8b;
    // prefetch Q s-tile (used in phase B)
    {
      const size_t off = ((size_t)bh * L + s0 + srow) * E + scol;
      qh8a = *(const bf16x8*)(Qh + off);
      qh8b = *(const bf16x8*)(Qh + off + 8);
      ql8a = *(const bf16x8*)(Ql + off);
      ql8b = *(const bf16x8*)(Ql + off + 8);
    }
    __syncthreads();

    // T1: D1[l][s] = Q[l]·K[s]   (order: qh·kh, qh·kl, ql·kh)
    f32x4 acc1[2] = {}, acc2[2] = {};
#pragma unroll
    for (int nt = 0; nt < 2; ++nt) {
      const int brow = sh * 32 + nt * 16 + c;
#pragma unroll
      for (int ks = 0; ks < 2; ++ks) {
        bf16x8 bhv = *(const bf16x8*)&KQh[brow][ks * 32 + qd * 8];
        bf16x8 blv = *(const bf16x8*)&KQl[brow][ks * 32 + qd * 8];
        acc1[nt] = mfma16(qaf[ks][0], bhv, acc1[nt]);
        acc1[nt] = mfma16(qaf[ks][0], blv, acc1[nt]);
        acc1[nt] = mfma16(qaf[ks][1], bhv, acc1[nt]);
      }
    }
    __syncthreads();  // T1 reads done

    // phase B: overwrite KQ with Q s-tile planes
    *(bf16x8*)&KQh[srow][scol]     = qh8a;
    *(bf16x8*)&KQh[srow][scol + 8] = qh8b;
    *(bf16x8*)&KQl[srow][scol]     = ql8a;
    *(bf16x8*)&KQl[srow][scol + 8] = ql8b;
    // prefetch next iteration's K + VT tiles
    {
      const size_t off = ((size_t)bh * L + s0n + srow) * E + scol;
      kh8a = *(const bf16x8*)(Kh + off);
      kh8b = *(const bf16x8*)(Kh + off + 8);
      kl8a = *(const bf16x8*)(Kl + off);
      kl8b = *(const bf16x8*)(Kl + off + 8);
      const size_t voff = ((size_t)bh * E + srow) * L + s0n + scol;
      vt8a = *(const bf16x8*)(VT + voff);
      vt8b = *(const bf16x8*)(VT + voff + 8);
    }
    __syncthreads();

    // T2: D2[l][s] = K[l]·Q[s]   (order: kh·qh, kl·qh, kh·ql — matches T1
    // term values at the diagonal -> Aa bitwise 0 -> att diag exactly 0)
#pragma unroll
    for (int nt = 0; nt < 2; ++nt) {
      const int brow = sh * 32 + nt * 16 + c;
#pragma unroll
      for (int ks = 0; ks < 2; ++ks) {
        bf16x8 qbh = *(const bf16x8*)&KQh[brow][ks * 32 + qd * 8];
        bf16x8 qbl = *(const bf16x8*)&KQl[brow][ks * 32 + qd * 8];
        acc2[nt] = mfma16(kaf[ks][0], qbh, acc2[nt]);
        acc2[nt] = mfma16(kaf[ks][1], qbh, acc2[nt]);
        acc2[nt] = mfma16(kaf[ks][0], qbl, acc2[nt]);
      }
    }

    // transform (register-local), att store, attL, entropy (log2 domain)
    float* arow = attg + ((size_t)bh * L + l0 + lh * 16 + qd * 4) * L + s0 + sh * 32;
#pragma unroll
    for (int nt = 0; nt < 2; ++nt) {
#pragma unroll
      for (int r = 0; r < 4; ++r) {
        float u = acc1[nt][r] + acc2[nt][r];        // 16*S_sym
        float d = acc1[nt][r] - acc2[nt][r];        // 16*A_anti
        float th1 = 1.f - 2.f * rcp_fast(exp2_fast(u * A1) + 1.f);
        float gate = rcp_fast(1.f + exp2_fast(th1 * G1));
        float th2 = 1.f - 2.f * rcp_fast(exp2_fast(d * A2) + 1.f);
        float dir  = rcp_fast(1.f + exp2_fast(th2 * G2));
        float t    = 1.f - 2.f * rcp_fast(exp2_fast(d * A3) + 1.f);
        float a = fmaxf(t, 0.0f) * gate * dir;
        ent[r] -= a * log2_fast(fmaxf(a, 1e-8f));
        arow[(size_t)r * L + nt * 16 + c] = a;
        attL[w * 16 + qd * 4 + r][nt * 16 + c] = (bf16_t)a;
      }
    }
    // wave-local D-layout -> A-layout exchange (no cross-wave sharing)
    __threadfence_block();

    // PV
    bf16x8 af = *(const bf16x8*)&attL[w * 16 + c][qd * 8];
#pragma unroll
    for (int ne = 0; ne < 4; ++ne) {
      bf16x8 bv = *(const bf16x8*)&Vt[ne * 16 + c][sh * 32 + qd * 8];
      accv[ne] = mfma16(af, bv, accv[ne]);
    }
  }

  // ---- epilogue: combine s-halves, atomic into global (s-split blocks) ----
  __syncthreads();
  float* red = (float*)smem;  // [2][16][68] f32, aliases KQh (dead)
  if (sh == 1) {
#pragma unroll
    for (int ne = 0; ne < 4; ++ne)
#pragma unroll
      for (int r = 0; r < 4; ++r)
        red[((size_t)lh * 16 + qd * 4 + r) * 68 + ne * 16 + c] = accv[ne][r];
  }
  __syncthreads();
  if (sh == 0) {
#pragma unroll
    for (int ne = 0; ne < 4; ++ne)
#pragma unroll
      for (int r = 0; r < 4; ++r) {
        float val = accv[ne][r] +
                    red[((size_t)lh * 16 + qd * 4 + r) * 68 + ne * 16 + c];
        atomicAdd(Vout + ((size_t)(b * L + l0 + lh * 16 + qd * 4 + r) * H + h) * E +
                      ne * 16 + c,
                  val);
      }
  }
#pragma unroll
  for (int r = 0; r < 4; ++r) {
    float e = ent[r];
    e += __shfl_xor(e, 1);
    e += __shfl_xor(e, 2);
    e += __shfl_xor(e, 4);
    e += __shfl_xor(e, 8);
    if (c == 0)
      atomicAdd(entr + (size_t)bh * L + l0 + lh * 16 + qd * 4 + r, e * LN2);
  }
}

// ===========================================================================
// Fallback (R2 kernel) if ws_size is too small for the planes.
// ===========================================================================
__device__ __forceinline__ float tanh_fast(float x) {
  return 1.0f - 2.0f * rcp_fast(__expf(2.0f * x) + 1.0f);
}
__device__ __forceinline__ float sigm_fast(float x) {
  return rcp_fast(1.0f + __expf(-x));
}
__device__ __forceinline__ void split_store(bf16_t* hi, bf16_t* lo, float4 x) {
  bf16x4 hv, lv;
  split4(x, hv, lv);
  *(bf16x4*)hi = hv;
  *(bf16x4*)lo = lv;
}

__global__ __launch_bounds__(128, 1) void fused_attn(
    const float* __restrict__ q, const float* __restrict__ kk,
    const float* __restrict__ v,
    float* __restrict__ Vout, float* __restrict__ attg, float* __restrict__ entr,
    const float* __restrict__ p_lgg, const float* __restrict__ p_ltg,
    const float* __restrict__ p_lgd, const float* __restrict__ p_ltd)
{
  constexpr int TM = 32;
  __shared__ bf16_t Qa_hi[TM][72], Qa_lo[TM][72];
  __shared__ bf16_t Ka_hi[TM][72], Ka_lo[TM][72];
  __shared__ bf16_t KQ_hi[64][72], KQ_lo[64][72];
  __shared__ bf16_t Vts[64][72];
  __shared__ float  T2ex[2][64][17];
  __shared__ bf16_t attLs[2][16][72];

  const int tid = threadIdx.x;
  const int w = tid >> 6;
  const int lane = tid & 63;
  const int c = lane & 15;
  const int qd = lane >> 4;
  const int t8 = tid >> 4;
  const int c4 = tid & 15;
  const int lt = blockIdx.x;
  const int bh = blockIdx.y;
  const int b = bh >> 3, h = bh & 7;
  const int l0 = lt * TM;

  const float gg = fminf(fmaxf(__expf(p_lgg[0]), 1e-3f), 20.0f);
  const float tg = fminf(fmaxf(__expf(p_ltg[0]), 1e-3f), 10.0f);
  const float gd = fminf(fmaxf(__expf(p_lgd[0]), 1e-3f), 20.0f);
  const float td = fminf(fmaxf(__expf(p_ltd[0]), 1e-3f), 10.0f);
  const float inv_tg = 1.0f / tg;
  const float inv_td = 1.0f / td;
  const float gd_inv_td = gd * inv_td;

  const float* qlbase = q  + ((size_t)(b * L + l0) * H + h) * E;
  const float* qsbase = q  + ((size_t)b * L * H + h) * E;
  const float* kbase  = kk + ((size_t)b * L * H + h) * E;
  const float* vbase  = v  + ((size_t)b * L * H + h) * E;

#pragma unroll
  for (int i = 0; i < 4; ++i) {
    int r = t8 + 8 * i;
    float4 qa = *(const float4*)(qlbase + (size_t)r * HE + c4 * 4);
    float4 ka = *(const float4*)(kbase + (size_t)(l0 + r) * HE + c4 * 4);
    split_store(&Qa_hi[r][c4 * 4], &Qa_lo[r][c4 * 4], qa);
    split_store(&Ka_hi[r][c4 * 4], &Ka_lo[r][c4 * 4], ka);
  }

  float4 kpre[8], qpre[8];
  float vpre[32];
#pragma unroll
  for (int i = 0; i < 8; ++i)
    kpre[i] = *(const float4*)(kbase + (size_t)(t8 + 8 * i) * HE + c4 * 4);
#pragma unroll
  for (int i = 0; i < 8; ++i)
    qpre[i] = *(const float4*)(qsbase + (size_t)(t8 + 8 * i) * HE + c4 * 4);
#pragma unroll
  for (int j = 0; j < 32; ++j)
    vpre[j] = vbase[(size_t)(w * 32 + j) * HE + lane];

  __syncthreads();

  bf16x8 qaf[2][2], kaf[2][2];
#pragma unroll
  for (int ks = 0; ks < 2; ++ks) {
    qaf[ks][0] = *(const bf16x8*)&Qa_hi[w * 16 + c][ks * 32 + qd * 8];
    qaf[ks][1] = *(const bf16x8*)&Qa_lo[w * 16 + c][ks * 32 + qd * 8];
    kaf[ks][0] = *(const bf16x8*)&Ka_hi[w * 16 + c][ks * 32 + qd * 8];
    kaf[ks][1] = *(const bf16x8*)&Ka_lo[w * 16 + c][ks * 32 + qd * 8];
  }

  f32x4 accv[4] = {};
  float ent[4] = {0.f, 0.f, 0.f, 0.f};
  const int gl_base = l0 + w * 16 + qd * 4;

  for (int it = 0; it < 16; ++it) {
    const int s0 = it * 64;
    const int snext = ((it + 1) & 15) * 64;

    __syncthreads();
#pragma unroll
    for (int i = 0; i < 8; ++i) {
      int r = t8 + 8 * i;
      split_store(&KQ_hi[r][c4 * 4], &KQ_lo[r][c4 * 4], kpre[i]);
    }
#pragma unroll
    for (int j = 0; j < 16; ++j) {
      bf16x2 p;
      p[0] = (bf16_t)vpre[2 * j];
      p[1] = (bf16_t)vpre[2 * j + 1];
      *(bf16x2*)&Vts[lane][w * 32 + 2 * j] = p;
    }
    __syncthreads();

#pragma unroll
    for (int i = 0; i < 8; ++i)
      kpre[i] = *(const float4*)(kbase + (size_t)(snext + t8 + 8 * i) * HE + c4 * 4);
#pragma unroll
    for (int j = 0; j < 32; ++j)
      vpre[j] = vbase[(size_t)(snext + w * 32 + j) * HE + lane];

    f32x4 acc1[4] = {};
#pragma unroll
    for (int nt = 0; nt < 4; ++nt) {
#pragma unroll
      for (int ks = 0; ks < 2; ++ks) {
        bf16x8 bhv = *(const bf16x8*)&KQ_hi[nt * 16 + c][ks * 32 + qd * 8];
        bf16x8 blv = *(const bf16x8*)&KQ_lo[nt * 16 + c][ks * 32 + qd * 8];
        acc1[nt] = mfma16(qaf[ks][0], bhv, acc1[nt]);
        acc1[nt] = mfma16(qaf[ks][0], blv, acc1[nt]);
        acc1[nt] = mfma16(qaf[ks][1], bhv, acc1[nt]);
      }
    }
    __syncthreads();

#pragma unroll
    for (int i = 0; i < 8; ++i) {
      int r = t8 + 8 * i;
      split_store(&KQ_hi[r][c4 * 4], &KQ_lo[r][c4 * 4], qpre[i]);
    }
    __syncthreads();

#pragma unroll
    for (int i = 0; i < 8; ++i)
      qpre[i] = *(const float4*)(qsbase + (size_t)(snext + t8 + 8 * i) * HE + c4 * 4);

    f32x4 acc2[4] = {};
#pragma unroll
    for (int mt = 0; mt < 4; ++mt) {
#pragma unroll
      for (int ks = 0; ks < 2; ++ks) {
        bf16x8 ahv = *(const bf16x8*)&KQ_hi[mt * 16 + c][ks * 32 + qd * 8];
        bf16x8 alv = *(const bf16x8*)&KQ_lo[mt * 16 + c][ks * 32 + qd * 8];
        acc2[mt] = mfma16(ahv, kaf[ks][0], acc2[mt]);
        acc2[mt] = mfma16(ahv, kaf[ks][1], acc2[mt]);
        acc2[mt] = mfma16(alv, kaf[ks][0], acc2[mt]);
      }
    }

#pragma unroll
    for (int mt = 0; mt < 4; ++mt)
#pragma unroll
      for (int r = 0; r < 4; ++r)
        T2ex[w][mt * 16 + qd * 4 + r][c] = acc2[mt][r];
    __syncthreads();

    float* attrow0 = attg + ((size_t)bh * L + gl_base) * L + s0;
#pragma unroll
    for (int nt = 0; nt < 4; ++nt) {
#pragma unroll
      for (int r = 0; r < 4; ++r) {
        float x = 0.125f * acc1[nt][r];
        float y = 0.125f * T2ex[w][nt * 16 + c][qd * 4 + r];
        float Ss = 0.5f * (x + y);
        float Aa = 0.5f * (x - y);
        float gate = sigm_fast(gg * tanh_fast(Ss * inv_tg));
        float dir  = sigm_fast(gd * tanh_fast(Aa * inv_td));
        float t    = tanh_fast(Aa * gd_inv_td);
        float a = fmaxf(t, 0.0f) * gate * dir;
        ent[r] -= a * __logf(fmaxf(a, 1e-8f));
        attrow0[(size_t)r * L + nt * 16 + c] = a;
        attLs[w][qd * 4 + r][nt * 16 + c] = (bf16_t)a;
      }
    }
    __syncthreads();

#pragma unroll
    for (int ks = 0; ks < 2; ++ks) {
      bf16x8 af = *(const bf16x8*)&attLs[w][c][ks * 32 + qd * 8];
#pragma unroll
      for (int ne = 0; ne < 4; ++ne) {
        bf16x8 bfv = *(const bf16x8*)&Vts[ne * 16 + c][ks * 32 + qd * 8];
        accv[ne] = mfma16(af, bfv, accv[ne]);
      }
    }
  }

#pragma unroll
  for (int r = 0; r < 4; ++r) {
    float* vb = Vout + ((size_t)(b * L + gl_base + r) * H + h) * E;
#pragma unroll
    for (int ne = 0; ne < 4; ++ne) vb[ne * 16 + c] = accv[ne][r];
    float e4 = ent[r];
    e4 += __shfl_xor(e4, 1);
    e4 += __shfl_xor(e4, 2);
    e4 += __shfl_xor(e4, 4);
    e4 += __shfl_xor(e4, 8);
    if (c == 0) entr[(size_t)bh * L + gl_base + r] = e4;
  }
}

}  // namespace

extern "C" void kernel_launch(void* const* d_in, const int* in_sizes, int n_in,
                              void* d_out, int out_size, void* d_ws, size_t ws_size,
                              hipStream_t stream) {
  const float* q = (const float*)d_in[0];
  const float* k = (const float*)d_in[1];
  const float* v = (const float*)d_in[2];
  const float* p_lgg = (const float*)d_in[7];
  const float* p_ltg = (const float*)d_in[8];
  const float* p_lgd = (const float*)d_in[9];
  const float* p_ltd = (const float*)d_in[10];

  float* Vout = (float*)d_out;          // (B,L,H,E)   1,048,576
  float* att  = Vout + 1048576;         // (B,H,L,S)  16,777,216
  float* entr = att + 16777216;         // (B,H,L)        16,384

  const size_t need = 5 * PL * sizeof(bf16_t);  // 10,485,760 B
  if (ws_size >= need) {
    bf16_t* ws = (bf16_t*)d_ws;
    k_prep<<<dim3(1296), 256, 0, stream>>>(q, k, v, ws, Vout, entr);
    k_main<<<dim3(32, 16, 4), 256, 0, stream>>>(
        ws, Vout, att, entr, p_lgg, p_ltg, p_lgd, p_ltd);
  } else {
    fused_attn<<<dim3(32, 16), 128, 0, stream>>>(
        q, k, v, Vout, att, entr, p_lgg, p_ltg, p_lgd, p_ltd);
  }
}